// Round 13
// baseline (259.357 us; speedup 1.0000x reference)
//
#include <hip/hip_runtime.h>

#define B_    64
#define N_    512
#define DIN_  256
#define DOUT_ 256
#define EPS_  1e-5f
#define ROWS_ (B_ * N_)   // 32768
#define NBLK_Y2 512

typedef __attribute__((ext_vector_type(8))) short bf16x8;   // 8 bf16 = 4 VGPRs
typedef __attribute__((ext_vector_type(8))) unsigned short u16x8;
typedef __attribute__((ext_vector_type(4))) float f32x4;
typedef __attribute__((ext_vector_type(4))) short short4v;

__device__ __forceinline__ short f2bf(float f) {
    unsigned u = __builtin_bit_cast(unsigned, f);
    u += 0x7fff + ((u >> 16) & 1);     // round-to-nearest-even
    return (short)(u >> 16);
}

// Fragment order: [kfrag][efrag/mfrag(16)][lane(64)][8 shorts].
// LDS slot swizzle: phys = s ^ ((s>>4)&3).

// WTf: W[k][e] -> fragment order.
__global__ __launch_bounds__(256) void wt_cvt(const float* __restrict__ W,
                                              short* __restrict__ WTf) {
    const int c = blockIdx.x * 256 + threadIdx.x;   // 0..8191
    const int kf = c >> 10, ef = (c >> 6) & 15, lp = c & 63;
    const int e = ef * 16 + (lp & 15);
    const int k0 = kf * 32 + (lp >> 4) * 8;
    bf16x8 h;
    #pragma unroll
    for (int j = 0; j < 8; ++j)
        h[j] = f2bf(W[(size_t)(k0 + j) * DOUT_ + e]);
    *(bf16x8*)&WTf[(size_t)c * 8] = h;
}

// xw = x @ W (R12 version, unchanged)
__global__ __launch_bounds__(512, 4) void gemm_xw(const float* __restrict__ X,
                                                  const short* __restrict__ WTf,
                                                  short* __restrict__ xwT) {
    __shared__ __align__(16) short As[8 * 4 * 64 * 8];   // 32 KB
    const int tid = threadIdx.x, wv = tid >> 6, lane = tid & 63;
    const int lrow = lane & 15, lg = lane >> 4;
    const int bid = blockIdx.x;
    const int rt = ((bid & 7) * 8 + ((bid >> 3) & 7)) * 8 + (bid >> 6);
    const int rowBase = rt * 64;

    #pragma unroll
    for (int j = 0; j < 8; ++j) {
        int g = tid + j * 512;
        int row = g >> 6, c4 = g & 63;
        float4 v = *(const float4*)&X[(size_t)(rowBase + row) * DIN_ + c4 * 4];
        short4v s4 = { f2bf(v.x), f2bf(v.y), f2bf(v.z), f2bf(v.w) };
        int kf = c4 >> 3, sub = (c4 >> 1) & 3;
        int s = kf * 256 + (row >> 4) * 64 + (row & 15) + 16 * sub;
        int phys = s ^ sub;
        *(short4v*)&As[phys * 8 + (c4 & 1) * 4] = s4;
    }
    __syncthreads();

    const int lx = lane ^ (lg & 3);
    const short* b0p = WTf + ((size_t)(wv * 2 + 0) * 64 + lane) * 8;
    const short* b1p = WTf + ((size_t)(wv * 2 + 1) * 64 + lane) * 8;
    bf16x8 bc0 = *(const bf16x8*)(b0p);
    bf16x8 bc1 = *(const bf16x8*)(b1p);
    f32x4 acc[4][2] = {};
    #pragma unroll 2
    for (int c = 0; c < 8; ++c) {
        const int cn = (c + 1 < 8) ? c + 1 : 7;
        bf16x8 bn0 = *(const bf16x8*)(b0p + cn * 8192);
        bf16x8 bn1 = *(const bf16x8*)(b1p + cn * 8192);
        const short* ab = &As[(c * 256 + lx) * 8];
        bf16x8 a0 = *(const bf16x8*)(ab);
        bf16x8 a1 = *(const bf16x8*)(ab + 512);
        bf16x8 a2 = *(const bf16x8*)(ab + 1024);
        bf16x8 a3 = *(const bf16x8*)(ab + 1536);
        acc[0][0] = __builtin_amdgcn_mfma_f32_16x16x32_bf16(a0, bc0, acc[0][0], 0, 0, 0);
        acc[0][1] = __builtin_amdgcn_mfma_f32_16x16x32_bf16(a0, bc1, acc[0][1], 0, 0, 0);
        acc[1][0] = __builtin_amdgcn_mfma_f32_16x16x32_bf16(a1, bc0, acc[1][0], 0, 0, 0);
        acc[1][1] = __builtin_amdgcn_mfma_f32_16x16x32_bf16(a1, bc1, acc[1][1], 0, 0, 0);
        acc[2][0] = __builtin_amdgcn_mfma_f32_16x16x32_bf16(a2, bc0, acc[2][0], 0, 0, 0);
        acc[2][1] = __builtin_amdgcn_mfma_f32_16x16x32_bf16(a2, bc1, acc[2][1], 0, 0, 0);
        acc[3][0] = __builtin_amdgcn_mfma_f32_16x16x32_bf16(a3, bc0, acc[3][0], 0, 0, 0);
        acc[3][1] = __builtin_amdgcn_mfma_f32_16x16x32_bf16(a3, bc1, acc[3][1], 0, 0, 0);
        bc0 = bn0; bc1 = bn1;
    }

    const int bz = rt >> 3, kfbase = (rt & 7) * 2;
    short* xwb = xwT + (size_t)bz * 131072;
    #pragma unroll
    for (int m = 0; m < 4; ++m)
        #pragma unroll
        for (int nf = 0; nf < 2; ++nf) {
            int kf = kfbase + (m >> 1);
            int ef = wv * 2 + nf;
            int lanep = lrow + 16 * ((m & 1) * 2 + (lg >> 1));
            size_t off = ((size_t)(kf * 16 + ef) * 64 + lanep) * 8 + (lg & 1) * 4;
            short4v o = { f2bf(acc[m][nf][0]), f2bf(acc[m][nf][1]),
                          f2bf(acc[m][nf][2]), f2bf(acc[m][nf][3]) };
            *(short4v*)&xwb[off] = o;
        }
}

// ======================= ABLATION VARIANTS (diagnostic) =======================
// V=0 full; V=1 no A-staging; V=2 no B-loads; V=3 no MFMA; V=4 staging only.
// Writes only to scratch (pcnt region) which the real kernel fully overwrites.
template <int V, int REP>
__global__ __launch_bounds__(512, 4) void gemm_abl(const float* __restrict__ adj,
                                                   const short* __restrict__ xwT,
                                                   float* __restrict__ scratch) {
    __shared__ __align__(16) short As[16 * 4 * 64 * 8];   // 64 KB, same as real
    const int tid = threadIdx.x, wv = tid >> 6, lane = tid & 63;
    const int bid = blockIdx.x;
    const int swz = ((bid & 7) << 6) | (bid >> 3);
    const int bz = swz >> 3, mt = swz & 7;
    const int rowBase = mt * 64;
    const float* A = adj + (size_t)bz * N_ * N_;
    const short* xwb = xwT + (size_t)bz * 131072;
    const int lx = lane ^ ((lane >> 4) & 3);
    float sink = 0.f;

    #pragma unroll 1
    for (int rep = 0; rep < REP; ++rep) {
        // launder pointers so repeated loads can't be hoisted/reused
        const float* Ar = A;
        const short* xr = xwb;
        asm volatile("" : "+v"(Ar), "+v"(xr));
        if constexpr (V != 1) {   // ---- A staging ----
            #pragma unroll
            for (int j = 0; j < 16; ++j) {
                int g = tid + j * 512;
                int row = g >> 7, c4 = g & 127;
                float4 v = *(const float4*)&Ar[(size_t)(rowBase + row) * N_ + c4 * 4];
                short4v s4 = { f2bf(v.x), f2bf(v.y), f2bf(v.z), f2bf(v.w) };
                int kf = c4 >> 3, sub = (c4 >> 1) & 3;
                int s = kf * 256 + (row >> 4) * 64 + (row & 15) + 16 * sub;
                int phys = s ^ sub;
                *(short4v*)&As[phys * 8 + (c4 & 1) * 4] = s4;
            }
        }
        __syncthreads();
        if constexpr (V != 4) {   // ---- K loop ----
            const short* b0p = xr + ((size_t)(wv * 2 + 0) * 64 + lane) * 8;
            const short* b1p = xr + ((size_t)(wv * 2 + 1) * 64 + lane) * 8;
            bf16x8 bpre[4][2];
            if constexpr (V != 2) {
                #pragma unroll
                for (int p = 0; p < 3; ++p) {
                    bpre[p][0] = *(const bf16x8*)(b0p + p * 8192);
                    bpre[p][1] = *(const bf16x8*)(b1p + p * 8192);
                }
            } else {
                #pragma unroll
                for (int p = 0; p < 4; ++p) {
                    bpre[p][0] = bf16x8{1, 2, 3, 4, 5, 6, 7, 8};
                    bpre[p][1] = bf16x8{8, 7, 6, 5, 4, 3, 2, 1};
                }
            }
            f32x4 acc[4][2] = {};
            #pragma unroll
            for (int c = 0; c < 16; ++c) {
                if constexpr (V != 2) {
                    const int cn = (c + 3 < 16) ? c + 3 : 15;
                    bpre[(c + 3) & 3][0] = *(const bf16x8*)(b0p + cn * 8192);
                    bpre[(c + 3) & 3][1] = *(const bf16x8*)(b1p + cn * 8192);
                }
                const short* abp = &As[(c * 256 + lx) * 8];
                bf16x8 a0 = *(const bf16x8*)(abp);
                bf16x8 a1 = *(const bf16x8*)(abp + 512);
                bf16x8 a2 = *(const bf16x8*)(abp + 1024);
                bf16x8 a3 = *(const bf16x8*)(abp + 1536);
                bf16x8 bc0 = bpre[c & 3][0];
                bf16x8 bc1 = bpre[c & 3][1];
                if constexpr (V != 3) {
                    acc[0][0] = __builtin_amdgcn_mfma_f32_16x16x32_bf16(a0, bc0, acc[0][0], 0, 0, 0);
                    acc[0][1] = __builtin_amdgcn_mfma_f32_16x16x32_bf16(a0, bc1, acc[0][1], 0, 0, 0);
                    acc[1][0] = __builtin_amdgcn_mfma_f32_16x16x32_bf16(a1, bc0, acc[1][0], 0, 0, 0);
                    acc[1][1] = __builtin_amdgcn_mfma_f32_16x16x32_bf16(a1, bc1, acc[1][1], 0, 0, 0);
                    acc[2][0] = __builtin_amdgcn_mfma_f32_16x16x32_bf16(a2, bc0, acc[2][0], 0, 0, 0);
                    acc[2][1] = __builtin_amdgcn_mfma_f32_16x16x32_bf16(a2, bc1, acc[2][1], 0, 0, 0);
                    acc[3][0] = __builtin_amdgcn_mfma_f32_16x16x32_bf16(a3, bc0, acc[3][0], 0, 0, 0);
                    acc[3][1] = __builtin_amdgcn_mfma_f32_16x16x32_bf16(a3, bc1, acc[3][1], 0, 0, 0);
                } else {
                    // keep loads live without MFMA (rule #17: anti-DCE sinks)
                    asm volatile("" :: "v"(*(const int*)&a0), "v"(*(const int*)&a1),
                                       "v"(*(const int*)&a2), "v"(*(const int*)&a3),
                                       "v"(*(const int*)&bc0), "v"(*(const int*)&bc1));
                }
            }
            sink += acc[0][0][0] + acc[1][1][1] + acc[2][0][2] + acc[3][1][3];
        }
        __syncthreads();
    }
    if (tid == 0) scratch[bid] = sink;   // overwritten by real kernel's pcnt
}

// =================== real pipeline (R12, proven, unchanged) ===================
__global__ __launch_bounds__(512, 4) void gemm_y2_stage(const float* __restrict__ adj,
                                                        const short* __restrict__ xwT,
                                                        const float* __restrict__ bias,
                                                        const float* __restrict__ mask,
                                                        unsigned short* __restrict__ y2b,
                                                        float* __restrict__ psum,
                                                        float* __restrict__ psumsq,
                                                        float* __restrict__ pcnt) {
    __shared__ __align__(16) short As[16 * 4 * 64 * 8];   // 64 KB
    const int tid = threadIdx.x, wv = tid >> 6, lane = tid & 63;
    const int lrow = lane & 15, lg = lane >> 4;
    const int bid = blockIdx.x;
    const int swz = ((bid & 7) << 6) | (bid >> 3);
    const int bz = swz >> 3, mt = swz & 7;
    const int rowBase = mt * 64;
    const float* A = adj + (size_t)bz * N_ * N_;
    const short* xwb = xwT + (size_t)bz * 131072;

    #pragma unroll
    for (int j = 0; j < 16; ++j) {
        int g = tid + j * 512;
        int row = g >> 7, c4 = g & 127;
        float4 v = *(const float4*)&A[(size_t)(rowBase + row) * N_ + c4 * 4];
        short4v s4 = { f2bf(v.x), f2bf(v.y), f2bf(v.z), f2bf(v.w) };
        int kf = c4 >> 3, sub = (c4 >> 1) & 3;
        int s = kf * 256 + (row >> 4) * 64 + (row & 15) + 16 * sub;
        int phys = s ^ sub;
        *(short4v*)&As[phys * 8 + (c4 & 1) * 4] = s4;
    }
    __syncthreads();

    const int lx = lane ^ (lg & 3);
    const short* b0p = xwb + ((size_t)(wv * 2 + 0) * 64 + lane) * 8;
    const short* b1p = xwb + ((size_t)(wv * 2 + 1) * 64 + lane) * 8;
    bf16x8 bpre[4][2];
    #pragma unroll
    for (int p = 0; p < 3; ++p) {
        bpre[p][0] = *(const bf16x8*)(b0p + p * 8192);
        bpre[p][1] = *(const bf16x8*)(b1p + p * 8192);
    }
    f32x4 acc[4][2] = {};
    #pragma unroll
    for (int c = 0; c < 16; ++c) {
        const int cn = (c + 3 < 16) ? c + 3 : 15;
        bpre[(c + 3) & 3][0] = *(const bf16x8*)(b0p + cn * 8192);
        bpre[(c + 3) & 3][1] = *(const bf16x8*)(b1p + cn * 8192);
        const short* abp = &As[(c * 256 + lx) * 8];
        bf16x8 a0 = *(const bf16x8*)(abp);
        bf16x8 a1 = *(const bf16x8*)(abp + 512);
        bf16x8 a2 = *(const bf16x8*)(abp + 1024);
        bf16x8 a3 = *(const bf16x8*)(abp + 1536);
        bf16x8 bc0 = bpre[c & 3][0];
        bf16x8 bc1 = bpre[c & 3][1];
        acc[0][0] = __builtin_amdgcn_mfma_f32_16x16x32_bf16(a0, bc0, acc[0][0], 0, 0, 0);
        acc[0][1] = __builtin_amdgcn_mfma_f32_16x16x32_bf16(a0, bc1, acc[0][1], 0, 0, 0);
        acc[1][0] = __builtin_amdgcn_mfma_f32_16x16x32_bf16(a1, bc0, acc[1][0], 0, 0, 0);
        acc[1][1] = __builtin_amdgcn_mfma_f32_16x16x32_bf16(a1, bc1, acc[1][1], 0, 0, 0);
        acc[2][0] = __builtin_amdgcn_mfma_f32_16x16x32_bf16(a2, bc0, acc[2][0], 0, 0, 0);
        acc[2][1] = __builtin_amdgcn_mfma_f32_16x16x32_bf16(a2, bc1, acc[2][1], 0, 0, 0);
        acc[3][0] = __builtin_amdgcn_mfma_f32_16x16x32_bf16(a3, bc0, acc[3][0], 0, 0, 0);
        acc[3][1] = __builtin_amdgcn_mfma_f32_16x16x32_bf16(a3, bc1, acc[3][1], 0, 0, 0);
    }

    unsigned short* Cb = y2b + (size_t)bz * N_ * DOUT_;
    float mv[4][4];
    #pragma unroll
    for (int m = 0; m < 4; ++m)
        #pragma unroll
        for (int r = 0; r < 4; ++r)
            mv[m][r] = mask[bz * N_ + rowBase + m * 16 + lg * 4 + r];
    float sv[2] = {0.f, 0.f}, sq[2] = {0.f, 0.f};
    #pragma unroll
    for (int nf = 0; nf < 2; ++nf) {
        const int col = wv * 32 + nf * 16 + lrow;
        const float bv = bias[col];
        #pragma unroll
        for (int m = 0; m < 4; ++m) {
            const int r0 = rowBase + m * 16 + lg * 4;
            #pragma unroll
            for (int r = 0; r < 4; ++r) {
                float v = acc[m][nf][r] + bv;
                Cb[(size_t)(r0 + r) * DOUT_ + col] = (unsigned short)f2bf(v);
                float vm = v * mv[m][r];
                sv[nf] += vm;
                sq[nf] = fmaf(v, vm, sq[nf]);
            }
        }
    }
    #pragma unroll
    for (int nf = 0; nf < 2; ++nf) {
        sv[nf] += __shfl_xor(sv[nf], 16); sv[nf] += __shfl_xor(sv[nf], 32);
        sq[nf] += __shfl_xor(sq[nf], 16); sq[nf] += __shfl_xor(sq[nf], 32);
    }
    const int pidx = bz * 8 + mt;
    if (lg == 0) {
        #pragma unroll
        for (int nf = 0; nf < 2; ++nf) {
            psum[(size_t)pidx * DOUT_ + wv * 32 + nf * 16 + lrow]   = sv[nf];
            psumsq[(size_t)pidx * DOUT_ + wv * 32 + nf * 16 + lrow] = sq[nf];
        }
    }
    if (wv == 0) {
        float cnt = mask[bz * N_ + rowBase + lane];
        #pragma unroll
        for (int i = 1; i < 64; i <<= 1) cnt += __shfl_xor(cnt, i);
        if (lane == 0) pcnt[pidx] = cnt;
    }
}

__global__ __launch_bounds__(256) void finalize2(const float* __restrict__ psum,
                                                 const float* __restrict__ psumsq,
                                                 const float* __restrict__ pcnt,
                                                 const float* __restrict__ gamma,
                                                 const float* __restrict__ beta,
                                                 float* __restrict__ scsh) {
    const int e = blockIdx.x, t = threadIdx.x;
    float s  = psum[(size_t)t * DOUT_ + e]   + psum[(size_t)(t + 256) * DOUT_ + e];
    float ss = psumsq[(size_t)t * DOUT_ + e] + psumsq[(size_t)(t + 256) * DOUT_ + e];
    float n  = pcnt[t] + pcnt[t + 256];
    #pragma unroll
    for (int i = 1; i < 64; i <<= 1) {
        s += __shfl_xor(s, i); ss += __shfl_xor(ss, i); n += __shfl_xor(n, i);
    }
    __shared__ float red[3][4];
    const int wv = t >> 6;
    if ((t & 63) == 0) { red[0][wv] = s; red[1][wv] = ss; red[2][wv] = n; }
    __syncthreads();
    if (t == 0) {
        s  = red[0][0] + red[0][1] + red[0][2] + red[0][3];
        ss = red[1][0] + red[1][1] + red[1][2] + red[1][3];
        n  = red[2][0] + red[2][1] + red[2][2] + red[2][3];
        float mean = s / n;
        float var = ss / n - mean * mean;
        float sc = rsqrtf(var + EPS_) * gamma[e];
        scsh[e] = sc;
        scsh[DOUT_ + e] = beta[e] - mean * sc;
    }
}

__global__ __launch_bounds__(256) void norm_relu_bf(const unsigned short* __restrict__ y2b,
                                                    const float* __restrict__ mask,
                                                    const float* __restrict__ scsh,
                                                    float* __restrict__ out) {
    const int nq = ROWS_ * (DOUT_ / 8);
    for (int q = blockIdx.x * blockDim.x + threadIdx.x; q < nq;
         q += gridDim.x * blockDim.x) {
        int e8 = (q & 31) * 8;
        int r = q >> 5;
        float m = mask[r];
        u16x8 uv = *(const u16x8*)&y2b[(size_t)q * 8];
        float4 sc0 = *(const float4*)&scsh[e8];
        float4 sc1 = *(const float4*)&scsh[e8 + 4];
        float4 sh0 = *(const float4*)&scsh[DOUT_ + e8];
        float4 sh1 = *(const float4*)&scsh[DOUT_ + e8 + 4];
        float4 o0, o1;
        #pragma unroll
        for (int j = 0; j < 4; ++j) {
            float f = __builtin_bit_cast(float, (unsigned)uv[j] << 16);
            (&o0.x)[j] = fmaxf(fmaf(f, (&sc0.x)[j], (&sh0.x)[j]) * m, 0.f);
        }
        #pragma unroll
        for (int j = 0; j < 4; ++j) {
            float f = __builtin_bit_cast(float, (unsigned)uv[j + 4] << 16);
            (&o1.x)[j] = fmaxf(fmaf(f, (&sc1.x)[j], (&sh1.x)[j]) * m, 0.f);
        }
        *(float4*)&out[(size_t)q * 8] = o0;
        *(float4*)&out[(size_t)q * 8 + 4] = o1;
    }
}

extern "C" void kernel_launch(void* const* d_in, const int* in_sizes, int n_in,
                              void* d_out, int out_size, void* d_ws, size_t ws_size,
                              hipStream_t stream) {
    const float* x      = (const float*)d_in[0];
    const float* adj    = (const float*)d_in[1];
    const float* mask   = (const float*)d_in[2];
    const float* weight = (const float*)d_in[3];
    const float* bias   = (const float*)d_in[4];
    const float* gamma  = (const float*)d_in[5];
    const float* beta   = (const float*)d_in[6];
    float* out = (float*)d_out;

    char* p = (char*)d_ws;
    short* WTf = (short*)p;                          p += 131072;
    short* xwT = (short*)p;                          p += (size_t)DOUT_ * ROWS_ * 2;
    unsigned short* y2b = (unsigned short*)p;        p += (size_t)ROWS_ * DOUT_ * 2;
    float* psum   = (float*)p;
    float* psumsq = psum + NBLK_Y2 * DOUT_;
    float* pcnt   = psumsq + NBLK_Y2 * DOUT_;   // 512 floats — abl scratch, fully
    float* scsh   = pcnt + NBLK_Y2;             // overwritten by real gemm_y2

    wt_cvt<<<32, 256, 0, stream>>>(weight, WTf);
    gemm_xw<<<512, 512, 0, stream>>>(x, WTf, xwT);

    // ---- diagnostic ablation dispatches (read via rocprof per-dispatch dur) ----
    gemm_abl<0, 3><<<512, 512, 0, stream>>>(adj, xwT, pcnt);   // full
    gemm_abl<1, 3><<<512, 512, 0, stream>>>(adj, xwT, pcnt);   // no A-staging
    gemm_abl<2, 3><<<512, 512, 0, stream>>>(adj, xwT, pcnt);   // no B-loads
    gemm_abl<3, 3><<<512, 512, 0, stream>>>(adj, xwT, pcnt);   // no MFMA
    gemm_abl<4, 8><<<512, 512, 0, stream>>>(adj, xwT, pcnt);   // staging only

    // ---- real pipeline (R12, unchanged) ----
    gemm_y2_stage<<<NBLK_Y2, 512, 0, stream>>>(adj, xwT, bias, mask, y2b,
                                               psum, psumsq, pcnt);
    finalize2<<<256, 256, 0, stream>>>(psum, psumsq, pcnt, gamma, beta, scsh);
    norm_relu_bf<<<2048, 256, 0, stream>>>(y2b, mask, scsh, out);
}

// Round 14
// 55.681 us; speedup vs baseline: 4.6579x; 4.6579x over previous
//
#include <hip/hip_runtime.h>

#define B_    64
#define N_    512
#define DIN_  256
#define DOUT_ 256
#define EPS_  1e-5f
#define ROWS_ (B_ * N_)   // 32768
#define NBLK_Y2 512

typedef __attribute__((ext_vector_type(8))) short bf16x8;   // 8 bf16 = 4 VGPRs
typedef __attribute__((ext_vector_type(8))) unsigned short u16x8;
typedef __attribute__((ext_vector_type(4))) float f32x4;
typedef __attribute__((ext_vector_type(4))) short short4v;

__device__ __forceinline__ short f2bf(float f) {
    unsigned u = __builtin_bit_cast(unsigned, f);
    u += 0x7fff + ((u >> 16) & 1);     // round-to-nearest-even
    return (short)(u >> 16);
}

// Fragment order: [kfrag][efrag/mfrag(16)][lane(64)][8 shorts].
// LDS slot swizzle (staging): phys = s ^ ((s>>4)&3).
// LDS epilogue-transpose swizzle: byte ^= (row&7)<<4.

// WTf: W[k][e] -> fragment order.
__global__ __launch_bounds__(256) void wt_cvt(const float* __restrict__ W,
                                              short* __restrict__ WTf) {
    const int c = blockIdx.x * 256 + threadIdx.x;   // 0..8191
    const int kf = c >> 10, ef = (c >> 6) & 15, lp = c & 63;
    const int e = ef * 16 + (lp & 15);
    const int k0 = kf * 32 + (lp >> 4) * 8;
    bf16x8 h;
    #pragma unroll
    for (int j = 0; j < 8; ++j)
        h[j] = f2bf(W[(size_t)(k0 + j) * DOUT_ + e]);
    *(bf16x8*)&WTf[(size_t)c * 8] = h;
}

// xw = x @ W (R12 version, unchanged — epilogue already 512B-coalesced)
__global__ __launch_bounds__(512, 4) void gemm_xw(const float* __restrict__ X,
                                                  const short* __restrict__ WTf,
                                                  short* __restrict__ xwT) {
    __shared__ __align__(16) short As[8 * 4 * 64 * 8];   // 32 KB
    const int tid = threadIdx.x, wv = tid >> 6, lane = tid & 63;
    const int lrow = lane & 15, lg = lane >> 4;
    const int bid = blockIdx.x;
    const int rt = ((bid & 7) * 8 + ((bid >> 3) & 7)) * 8 + (bid >> 6);
    const int rowBase = rt * 64;

    #pragma unroll
    for (int j = 0; j < 8; ++j) {
        int g = tid + j * 512;
        int row = g >> 6, c4 = g & 63;
        float4 v = *(const float4*)&X[(size_t)(rowBase + row) * DIN_ + c4 * 4];
        short4v s4 = { f2bf(v.x), f2bf(v.y), f2bf(v.z), f2bf(v.w) };
        int kf = c4 >> 3, sub = (c4 >> 1) & 3;
        int s = kf * 256 + (row >> 4) * 64 + (row & 15) + 16 * sub;
        int phys = s ^ sub;
        *(short4v*)&As[phys * 8 + (c4 & 1) * 4] = s4;
    }
    __syncthreads();

    const int lx = lane ^ (lg & 3);
    const short* b0p = WTf + ((size_t)(wv * 2 + 0) * 64 + lane) * 8;
    const short* b1p = WTf + ((size_t)(wv * 2 + 1) * 64 + lane) * 8;
    bf16x8 bc0 = *(const bf16x8*)(b0p);
    bf16x8 bc1 = *(const bf16x8*)(b1p);
    f32x4 acc[4][2] = {};
    #pragma unroll 2
    for (int c = 0; c < 8; ++c) {
        const int cn = (c + 1 < 8) ? c + 1 : 7;
        bf16x8 bn0 = *(const bf16x8*)(b0p + cn * 8192);
        bf16x8 bn1 = *(const bf16x8*)(b1p + cn * 8192);
        const short* ab = &As[(c * 256 + lx) * 8];
        bf16x8 a0 = *(const bf16x8*)(ab);
        bf16x8 a1 = *(const bf16x8*)(ab + 512);
        bf16x8 a2 = *(const bf16x8*)(ab + 1024);
        bf16x8 a3 = *(const bf16x8*)(ab + 1536);
        acc[0][0] = __builtin_amdgcn_mfma_f32_16x16x32_bf16(a0, bc0, acc[0][0], 0, 0, 0);
        acc[0][1] = __builtin_amdgcn_mfma_f32_16x16x32_bf16(a0, bc1, acc[0][1], 0, 0, 0);
        acc[1][0] = __builtin_amdgcn_mfma_f32_16x16x32_bf16(a1, bc0, acc[1][0], 0, 0, 0);
        acc[1][1] = __builtin_amdgcn_mfma_f32_16x16x32_bf16(a1, bc1, acc[1][1], 0, 0, 0);
        acc[2][0] = __builtin_amdgcn_mfma_f32_16x16x32_bf16(a2, bc0, acc[2][0], 0, 0, 0);
        acc[2][1] = __builtin_amdgcn_mfma_f32_16x16x32_bf16(a2, bc1, acc[2][1], 0, 0, 0);
        acc[3][0] = __builtin_amdgcn_mfma_f32_16x16x32_bf16(a3, bc0, acc[3][0], 0, 0, 0);
        acc[3][1] = __builtin_amdgcn_mfma_f32_16x16x32_bf16(a3, bc1, acc[3][1], 0, 0, 0);
        bc0 = bn0; bc1 = bn1;
    }

    const int bz = rt >> 3, kfbase = (rt & 7) * 2;
    short* xwb = xwT + (size_t)bz * 131072;
    #pragma unroll
    for (int m = 0; m < 4; ++m)
        #pragma unroll
        for (int nf = 0; nf < 2; ++nf) {
            int kf = kfbase + (m >> 1);
            int ef = wv * 2 + nf;
            int lanep = lrow + 16 * ((m & 1) * 2 + (lg >> 1));
            size_t off = ((size_t)(kf * 16 + ef) * 64 + lanep) * 8 + (lg & 1) * 4;
            short4v o = { f2bf(acc[m][nf][0]), f2bf(acc[m][nf][1]),
                          f2bf(acc[m][nf][2]), f2bf(acc[m][nf][3]) };
            *(short4v*)&xwb[off] = o;
        }
}

// y2[b] = adj[b] @ xw[b] + bias, fused masked stats.
// NEW EPILOGUE (from R13 ablation: epilogue was ~15µs of scattered 2B stores):
// acc -> LDS [row][col] bf16 (XOR (row&7)<<4) -> coalesced 16B/lane stores.
__global__ __launch_bounds__(512, 4) void gemm_y2_stage(const float* __restrict__ adj,
                                                        const short* __restrict__ xwT,
                                                        const float* __restrict__ bias,
                                                        const float* __restrict__ mask,
                                                        unsigned short* __restrict__ y2b,
                                                        float* __restrict__ psum,
                                                        float* __restrict__ psumsq,
                                                        float* __restrict__ pcnt) {
    __shared__ __align__(16) short As[16 * 4 * 64 * 8];   // 64 KB
    const int tid = threadIdx.x, wv = tid >> 6, lane = tid & 63;
    const int lrow = lane & 15, lg = lane >> 4;
    const int bid = blockIdx.x;
    const int swz = ((bid & 7) << 6) | (bid >> 3);   // XCD-chunked
    const int bz = swz >> 3, mt = swz & 7;
    const int rowBase = mt * 64;
    const float* A = adj + (size_t)bz * N_ * N_;
    const short* xwb = xwT + (size_t)bz * 131072;

    #pragma unroll
    for (int j = 0; j < 16; ++j) {
        int g = tid + j * 512;
        int row = g >> 7, c4 = g & 127;
        float4 v = *(const float4*)&A[(size_t)(rowBase + row) * N_ + c4 * 4];
        short4v s4 = { f2bf(v.x), f2bf(v.y), f2bf(v.z), f2bf(v.w) };
        int kf = c4 >> 3, sub = (c4 >> 1) & 3;
        int s = kf * 256 + (row >> 4) * 64 + (row & 15) + 16 * sub;
        int phys = s ^ sub;
        *(short4v*)&As[phys * 8 + (c4 & 1) * 4] = s4;
    }
    __syncthreads();

    const int lx = lane ^ (lg & 3);
    const short* b0p = xwb + ((size_t)(wv * 2 + 0) * 64 + lane) * 8;
    const short* b1p = xwb + ((size_t)(wv * 2 + 1) * 64 + lane) * 8;
    bf16x8 bpre[4][2];
    #pragma unroll
    for (int p = 0; p < 3; ++p) {
        bpre[p][0] = *(const bf16x8*)(b0p + p * 8192);
        bpre[p][1] = *(const bf16x8*)(b1p + p * 8192);
    }
    f32x4 acc[4][2] = {};
    #pragma unroll
    for (int c = 0; c < 16; ++c) {
        const int cn = (c + 3 < 16) ? c + 3 : 15;
        bpre[(c + 3) & 3][0] = *(const bf16x8*)(b0p + cn * 8192);
        bpre[(c + 3) & 3][1] = *(const bf16x8*)(b1p + cn * 8192);
        const short* abp = &As[(c * 256 + lx) * 8];
        bf16x8 a0 = *(const bf16x8*)(abp);
        bf16x8 a1 = *(const bf16x8*)(abp + 512);
        bf16x8 a2 = *(const bf16x8*)(abp + 1024);
        bf16x8 a3 = *(const bf16x8*)(abp + 1536);
        bf16x8 bc0 = bpre[c & 3][0];
        bf16x8 bc1 = bpre[c & 3][1];
        acc[0][0] = __builtin_amdgcn_mfma_f32_16x16x32_bf16(a0, bc0, acc[0][0], 0, 0, 0);
        acc[0][1] = __builtin_amdgcn_mfma_f32_16x16x32_bf16(a0, bc1, acc[0][1], 0, 0, 0);
        acc[1][0] = __builtin_amdgcn_mfma_f32_16x16x32_bf16(a1, bc0, acc[1][0], 0, 0, 0);
        acc[1][1] = __builtin_amdgcn_mfma_f32_16x16x32_bf16(a1, bc1, acc[1][1], 0, 0, 0);
        acc[2][0] = __builtin_amdgcn_mfma_f32_16x16x32_bf16(a2, bc0, acc[2][0], 0, 0, 0);
        acc[2][1] = __builtin_amdgcn_mfma_f32_16x16x32_bf16(a2, bc1, acc[2][1], 0, 0, 0);
        acc[3][0] = __builtin_amdgcn_mfma_f32_16x16x32_bf16(a3, bc0, acc[3][0], 0, 0, 0);
        acc[3][1] = __builtin_amdgcn_mfma_f32_16x16x32_bf16(a3, bc1, acc[3][1], 0, 0, 0);
    }

    // ---- epilogue: stats (shfl, unchanged) + LDS-transposed coalesced store ----
    float mv[4][4];
    #pragma unroll
    for (int m = 0; m < 4; ++m)
        #pragma unroll
        for (int r = 0; r < 4; ++r)
            mv[m][r] = mask[bz * N_ + rowBase + m * 16 + lg * 4 + r];

    __syncthreads();   // all waves done reading As; reuse as [64][256] bf16

    float sv[2] = {0.f, 0.f}, sq[2] = {0.f, 0.f};
    #pragma unroll
    for (int nf = 0; nf < 2; ++nf) {
        const int col = wv * 32 + nf * 16 + lrow;
        const float bv = bias[col];
        #pragma unroll
        for (int m = 0; m < 4; ++m) {
            #pragma unroll
            for (int r = 0; r < 4; ++r) {
                const int row = m * 16 + lg * 4 + r;
                float v = acc[m][nf][r] + bv;
                int byte = (row * 512 + col * 2) ^ ((row & 7) << 4);
                *(short*)((char*)As + byte) = f2bf(v);
                float vm = v * mv[m][r];
                sv[nf] += vm;
                sq[nf] = fmaf(v, vm, sq[nf]);
            }
        }
    }
    #pragma unroll
    for (int nf = 0; nf < 2; ++nf) {
        sv[nf] += __shfl_xor(sv[nf], 16); sv[nf] += __shfl_xor(sv[nf], 32);
        sq[nf] += __shfl_xor(sq[nf], 16); sq[nf] += __shfl_xor(sq[nf], 32);
    }
    const int pidx = bz * 8 + mt;
    if (lg == 0) {
        #pragma unroll
        for (int nf = 0; nf < 2; ++nf) {
            psum[(size_t)pidx * DOUT_ + wv * 32 + nf * 16 + lrow]   = sv[nf];
            psumsq[(size_t)pidx * DOUT_ + wv * 32 + nf * 16 + lrow] = sq[nf];
        }
    }
    if (wv == 0) {
        float cnt = mask[bz * N_ + rowBase + lane];
        #pragma unroll
        for (int i = 1; i < 64; i <<= 1) cnt += __shfl_xor(cnt, i);
        if (lane == 0) pcnt[pidx] = cnt;
    }
    __syncthreads();

    // coalesced store: 16B/lane, 512B contiguous per row
    unsigned short* Cb = y2b + ((size_t)bz * N_ + rowBase) * DOUT_;
    #pragma unroll
    for (int it = 0; it < 4; ++it) {
        int q = tid + it * 512;              // 0..2047 chunks of 16B
        int row = q >> 5, ch = q & 31;
        int byte = (row * 512 + ch * 16) ^ ((row & 7) << 4);
        u16x8 v = *(const u16x8*)((char*)As + byte);
        *(u16x8*)&Cb[(size_t)row * DOUT_ + ch * 8] = v;
    }
}

__global__ __launch_bounds__(256) void finalize2(const float* __restrict__ psum,
                                                 const float* __restrict__ psumsq,
                                                 const float* __restrict__ pcnt,
                                                 const float* __restrict__ gamma,
                                                 const float* __restrict__ beta,
                                                 float* __restrict__ scsh) {
    const int e = blockIdx.x, t = threadIdx.x;
    float s  = psum[(size_t)t * DOUT_ + e]   + psum[(size_t)(t + 256) * DOUT_ + e];
    float ss = psumsq[(size_t)t * DOUT_ + e] + psumsq[(size_t)(t + 256) * DOUT_ + e];
    float n  = pcnt[t] + pcnt[t + 256];
    #pragma unroll
    for (int i = 1; i < 64; i <<= 1) {
        s += __shfl_xor(s, i); ss += __shfl_xor(ss, i); n += __shfl_xor(n, i);
    }
    __shared__ float red[3][4];
    const int wv = t >> 6;
    if ((t & 63) == 0) { red[0][wv] = s; red[1][wv] = ss; red[2][wv] = n; }
    __syncthreads();
    if (t == 0) {
        s  = red[0][0] + red[0][1] + red[0][2] + red[0][3];
        ss = red[1][0] + red[1][1] + red[1][2] + red[1][3];
        n  = red[2][0] + red[2][1] + red[2][2] + red[2][3];
        float mean = s / n;
        float var = ss / n - mean * mean;
        float sc = rsqrtf(var + EPS_) * gamma[e];
        scsh[e] = sc;
        scsh[DOUT_ + e] = beta[e] - mean * sc;
    }
}

// out = relu((bf16(y2)*scale + shift) * mask), bf16 in -> f32 out
__global__ __launch_bounds__(256) void norm_relu_bf(const unsigned short* __restrict__ y2b,
                                                    const float* __restrict__ mask,
                                                    const float* __restrict__ scsh,
                                                    float* __restrict__ out) {
    const int nq = ROWS_ * (DOUT_ / 8);
    for (int q = blockIdx.x * blockDim.x + threadIdx.x; q < nq;
         q += gridDim.x * blockDim.x) {
        int e8 = (q & 31) * 8;
        int r = q >> 5;
        float m = mask[r];
        u16x8 uv = *(const u16x8*)&y2b[(size_t)q * 8];
        float4 sc0 = *(const float4*)&scsh[e8];
        float4 sc1 = *(const float4*)&scsh[e8 + 4];
        float4 sh0 = *(const float4*)&scsh[DOUT_ + e8];
        float4 sh1 = *(const float4*)&scsh[DOUT_ + e8 + 4];
        float4 o0, o1;
        #pragma unroll
        for (int j = 0; j < 4; ++j) {
            float f = __builtin_bit_cast(float, (unsigned)uv[j] << 16);
            (&o0.x)[j] = fmaxf(fmaf(f, (&sc0.x)[j], (&sh0.x)[j]) * m, 0.f);
        }
        #pragma unroll
        for (int j = 0; j < 4; ++j) {
            float f = __builtin_bit_cast(float, (unsigned)uv[j + 4] << 16);
            (&o1.x)[j] = fmaxf(fmaf(f, (&sc1.x)[j], (&sh1.x)[j]) * m, 0.f);
        }
        *(float4*)&out[(size_t)q * 8] = o0;
        *(float4*)&out[(size_t)q * 8 + 4] = o1;
    }
}

extern "C" void kernel_launch(void* const* d_in, const int* in_sizes, int n_in,
                              void* d_out, int out_size, void* d_ws, size_t ws_size,
                              hipStream_t stream) {
    const float* x      = (const float*)d_in[0];
    const float* adj    = (const float*)d_in[1];
    const float* mask   = (const float*)d_in[2];
    const float* weight = (const float*)d_in[3];
    const float* bias   = (const float*)d_in[4];
    const float* gamma  = (const float*)d_in[5];
    const float* beta   = (const float*)d_in[6];
    float* out = (float*)d_out;

    char* p = (char*)d_ws;
    short* WTf = (short*)p;                          p += 131072;
    short* xwT = (short*)p;                          p += (size_t)DOUT_ * ROWS_ * 2;
    unsigned short* y2b = (unsigned short*)p;        p += (size_t)ROWS_ * DOUT_ * 2;
    float* psum   = (float*)p;
    float* psumsq = psum + NBLK_Y2 * DOUT_;
    float* pcnt   = psumsq + NBLK_Y2 * DOUT_;
    float* scsh   = pcnt + NBLK_Y2;

    wt_cvt<<<32, 256, 0, stream>>>(weight, WTf);
    gemm_xw<<<512, 512, 0, stream>>>(x, WTf, xwT);
    gemm_y2_stage<<<NBLK_Y2, 512, 0, stream>>>(adj, xwT, bias, mask, y2b,
                                               psum, psumsq, pcnt);
    finalize2<<<256, 256, 0, stream>>>(psum, psumsq, pcnt, gamma, beta, scsh);
    norm_relu_bf<<<2048, 256, 0, stream>>>(y2b, mask, scsh, out);
}